// Round 3
// baseline (1844.430 us; speedup 1.0000x reference)
//
#include <hip/hip_runtime.h>

#define F_N   150000
#define K_N   5
#define S_N   32
#define V_N   100000
#define NITER 5
#define MLP_N 330
#define SHIFTV (-500.0f)

#define FBLK  ((F_N + 255) / 256)       // 587
#define VBLK  ((V_N + 255) / 256)       // 391
#define GBLK  ((V_N * 8 + 255) / 256)   // 3125  (8 threads per variable)
#define EBLK  ((F_N * K_N + 255) / 256) // 2930

__device__ __forceinline__ float lse2(float a, float b) {
    float mx = fmaxf(a, b);
    return mx + __logf(__expf(a - mx) + __expf(b - mx));
}

// ---------------- CSR build ------------------------------------------------
__global__ __launch_bounds__(256) void k_hist(
    const int* __restrict__ vidx, int* __restrict__ cnt)
{
    int i = blockIdx.x * 256 + threadIdx.x;
    if (i < F_N * K_N) atomicAdd(&cnt[vidx[i]], 1);
}

__global__ __launch_bounds__(256) void k_bsum(
    const int* __restrict__ cnt, int* __restrict__ bsum)
{
    __shared__ int s[256];
    int v = blockIdx.x * 256 + threadIdx.x;
    s[threadIdx.x] = (v < V_N) ? cnt[v] : 0;
    __syncthreads();
    #pragma unroll
    for (int off = 128; off >= 1; off >>= 1) {
        if (threadIdx.x < off) s[threadIdx.x] += s[threadIdx.x + off];
        __syncthreads();
    }
    if (threadIdx.x == 0) bsum[blockIdx.x] = s[0];
}

__global__ __launch_bounds__(256) void k_off(
    const int* __restrict__ cnt, const int* __restrict__ bsum,
    int* __restrict__ offsets)
{
    __shared__ int s[256];
    __shared__ int pre;
    int b = blockIdx.x, t = threadIdx.x;
    int acc = 0;
    for (int i = t; i < b; i += 256) acc += bsum[i];
    s[t] = acc; __syncthreads();
    #pragma unroll
    for (int off = 128; off >= 1; off >>= 1) {
        if (t < off) s[t] += s[t + off];
        __syncthreads();
    }
    if (t == 0) pre = s[0];
    __syncthreads();
    int base = pre;
    int v = b * 256 + t;
    int c = (v < V_N) ? cnt[v] : 0;
    s[t] = c; __syncthreads();
    #pragma unroll
    for (int off = 1; off < 256; off <<= 1) {
        int add = (t >= off) ? s[t - off] : 0;
        __syncthreads();
        s[t] += add;
        __syncthreads();
    }
    if (v < V_N) offsets[v] = base + s[t] - c;
}

__global__ __launch_bounds__(256) void k_fill(
    const int* __restrict__ vidx, const int* __restrict__ offsets,
    int* __restrict__ fillc, int* __restrict__ entries)
{
    int i = blockIdx.x * 256 + threadIdx.x;
    if (i >= F_N * K_N) return;
    int v = vidx[i];
    int f = i / K_N;
    int k = i - f * K_N;
    int pos = atomicAdd(&fillc[v], 1);
    entries[offsets[v] + pos] = k * F_N + f;   // pair-index into float2 m[5][F]
}

// ---------------- K0: m_1 from (prv_fb, prv_v2f) — no atomics ---------------
__global__ __launch_bounds__(256) void k_init(
    const float* __restrict__ prv_fb,   // [F][32]
    const float* __restrict__ prv_v2f,  // [F][5][2]
    float2*      __restrict__ m_out)    // [5][F] float2
{
    int f = blockIdx.x * 256 + threadIdx.x;
    if (f >= F_N) return;

    float fb[S_N];
    const float4* p4 = reinterpret_cast<const float4*>(prv_fb + (size_t)f * S_N);
    #pragma unroll
    for (int i = 0; i < S_N / 4; ++i) {
        float4 v = p4[i];
        fb[i*4+0] = v.x; fb[i*4+1] = v.y; fb[i*4+2] = v.z; fb[i*4+3] = v.w;
    }
    float M = fb[0];
    #pragma unroll
    for (int s = 1; s < S_N; ++s) M = fmaxf(M, fb[s]);
    float T = 0.0f;
    float S0[K_N] = {0.f, 0.f, 0.f, 0.f, 0.f};
    #pragma unroll
    for (int s = 0; s < S_N; ++s) {
        float t = __expf(fb[s] - M);
        T += t;
        #pragma unroll
        for (int k = 0; k < K_N; ++k)
            if (((s >> k) & 1) == 0) S0[k] += t;
    }
    #pragma unroll
    for (int k = 0; k < K_N; ++k) {
        float v0 = prv_v2f[(size_t)f * (K_N*2) + k*2 + 0];
        float v1 = prv_v2f[(size_t)f * (K_N*2) + k*2 + 1];
        float u0 = __logf(S0[k])     - v0;
        float u1 = __logf(T - S0[k]) - v1;
        float l  = lse2(u0, u1);
        m_out[k*F_N + f] = make_float2(u0 - l, u1 - l);
    }
}

// ---------------- per-iteration gather: vb_i = segsum(m_i); var_term_i ------
// 8 threads per variable: serial chain ~1 edge, then 3-level shuffle reduce.
__global__ __launch_bounds__(256) void k_gather(
    const float2* __restrict__ m,        // [5][F]
    const int*    __restrict__ cnt,      // [V] (= deg)
    const int*    __restrict__ offsets,  // [V]
    const int*    __restrict__ entries,  // [F*K]
    float2*       __restrict__ vb,       // [V] raw (unnormalized)
    float*        __restrict__ x,        // [330]
    int iter)
{
    int t = blockIdx.x * 256 + threadIdx.x;
    int v = t >> 3, sub = t & 7;
    int lane = threadIdx.x & 63;
    float a0 = 0.0f, a1 = 0.0f;
    int n = 0;
    if (v < V_N) {
        int off = offsets[v];
        n = cnt[v];
        for (int i = sub; i < n; i += 8) {
            float2 mm = m[entries[off + i]];
            a0 += mm.x; a1 += mm.y;
        }
    }
    #pragma unroll
    for (int mk = 1; mk < 8; mk <<= 1) {
        a0 += __shfl_xor(a0, mk);
        a1 += __shfl_xor(a1, mk);
    }
    float c0 = 0.0f, c1 = 0.0f;
    if (v < V_N && sub == 0) {
        vb[v] = make_float2(a0, a1);
        float l = lse2(a0, a1);
        float vb0 = a0 - l, vb1 = a1 - l;
        float dm1 = (float)n - 1.0f;
        c0 = dm1 * __expf(vb0) * vb0;
        c1 = dm1 * __expf(vb1) * vb1;
    }
    #pragma unroll
    for (int mk = 32; mk >= 1; mk >>= 1) {
        c0 += __shfl_xor(c0, mk);
        c1 += __shfl_xor(c1, mk);
    }
    if (lane == 0 && (c0 != 0.0f || c1 != 0.0f)) {
        atomicAdd(&x[iter*66 + 64], c0);
        atomicAdd(&x[iter*66 + 65], c1);
    }
}

// ---------------- fused factor iteration (no vb atomics) --------------------
template <bool LAST>
__global__ __launch_bounds__(256) void k_iter(
    const float*  __restrict__ pot,      // [F][32]
    const int*    __restrict__ vidx,     // [F][5]
    float2*       __restrict__ m,        // [5][F], updated in place
    const float2* __restrict__ vb,       // [V] raw
    float*        __restrict__ x,        // [330]
    int iter)
{
    const int lane = threadIdx.x & 63;
    __shared__ float red[256];

    int f = blockIdx.x * 256 + threadIdx.x;
    bool valid = f < F_N;
    int fc = valid ? f : (F_N - 1);

    float2 mm[K_N];
    #pragma unroll
    for (int k = 0; k < K_N; ++k) mm[k] = m[k*F_N + fc];
    int vi[K_N];
    #pragma unroll
    for (int k = 0; k < K_N; ++k) vi[k] = vidx[(size_t)fc * K_N + k];

    float v2f[K_N][2];
    #pragma unroll
    for (int k = 0; k < K_N; ++k) {
        float2 b = vb[vi[k]];
        float a0 = b.x - mm[k].x;
        float a1 = b.y - mm[k].y;
        float l = lse2(a0, a1);
        v2f[k][0] = a0 - l;
        v2f[k][1] = a1 - l;
    }

    float potr[S_N];
    const float4* p4 = reinterpret_cast<const float4*>(pot + (size_t)fc * S_N);
    #pragma unroll
    for (int i = 0; i < S_N / 4; ++i) {
        float4 v = p4[i];
        potr[i*4+0] = v.x; potr[i*4+1] = v.y; potr[i*4+2] = v.z; potr[i*4+3] = v.w;
    }

    float fb[S_N];
    #pragma unroll
    for (int s = 0; s < S_N; ++s) {
        float w = v2f[0][s & 1] + v2f[1][(s >> 1) & 1] + v2f[2][(s >> 2) & 1]
                + v2f[3][(s >> 3) & 1] + v2f[4][(s >> 4) & 1];
        fb[s] = potr[s] + w;
    }
    float M = fb[0];
    #pragma unroll
    for (int s = 1; s < S_N; ++s) M = fmaxf(M, fb[s]);

    float T = 0.0f;
    float S0[K_N] = {0.f, 0.f, 0.f, 0.f, 0.f};
    #pragma unroll
    for (int s = 0; s < S_N; ++s) {
        float t = __expf(fb[s] - M);
        T += t;
        #pragma unroll
        for (int k = 0; k < K_N; ++k)
            if (((s >> k) & 1) == 0) S0[k] += t;
    }

    if (!LAST) {
        #pragma unroll
        for (int k = 0; k < K_N; ++k) {
            float u0 = __logf(S0[k])     - v2f[k][0];
            float u1 = __logf(T - S0[k]) - v2f[k][1];
            float l  = lse2(u0, u1);
            if (valid) m[k*F_N + f] = make_float2(u0 - l, u1 - l);
        }
    }

    // ---- pooled features: energy[32] | fac_ent[32] ----
    float invT = 1.0f / T;
    float logT = __logf(T);
    float arr[2 * S_N];
    #pragma unroll
    for (int s = 0; s < S_N; ++s) {
        float p   = __expf(fb[s] - M) * invT;   // exp(fb_norm)
        float fbn = fb[s] - M - logT;           // normalized fb
        arr[s]       = valid ? p * potr[s] : 0.0f;
        arr[S_N + s] = valid ? -p * fbn    : 0.0f;
    }

    // recursive-halving reduce: 64 values over 64 lanes -> lane L holds sum of value L
    #pragma unroll
    for (int mk = 32; mk >= 1; mk >>= 1) {
        bool upper = (lane & mk) != 0;
        #pragma unroll
        for (int j = 0; j < mk; ++j) {
            float send = upper ? arr[j] : arr[j + mk];
            float recv = __shfl_xor(send, mk);
            float keep = upper ? arr[j + mk] : arr[j];
            arr[j] = keep + recv;
        }
    }

    red[threadIdx.x] = arr[0];
    __syncthreads();
    if (threadIdx.x < 64) {
        float s = red[threadIdx.x] + red[64 + threadIdx.x]
                + red[128 + threadIdx.x] + red[192 + threadIdx.x];
        atomicAdd(&x[iter*66 + threadIdx.x], s);
    }
}

// ---------------- MLP -------------------------------------------------------
__global__ __launch_bounds__(64) void k_mlp1(
    const float* __restrict__ x, const float* __restrict__ w1,
    const float* __restrict__ b1, float* __restrict__ h)
{
    int j = blockIdx.x;
    int lane = threadIdx.x;
    float s = 0.0f;
    for (int i = lane; i < MLP_N; i += 64) s += x[i] * w1[(size_t)j * MLP_N + i];
    #pragma unroll
    for (int mk = 32; mk >= 1; mk >>= 1) s += __shfl_xor(s, mk);
    if (lane == 0) h[j] = fmaxf(s + b1[j], SHIFTV);
}

__global__ __launch_bounds__(64) void k_mlp2(
    const float* __restrict__ h, const float* __restrict__ w2,
    const float* __restrict__ b2, float* __restrict__ out)
{
    int lane = threadIdx.x;
    float s = 0.0f;
    for (int i = lane; i < MLP_N; i += 64) s += h[i] * w2[i];
    #pragma unroll
    for (int mk = 32; mk >= 1; mk >>= 1) s += __shfl_xor(s, mk);
    if (lane == 0) out[0] = fmaxf(s + b2[0], SHIFTV);
}

// ---------------- launch -----------------------------------------------------
extern "C" void kernel_launch(void* const* d_in, const int* in_sizes, int n_in,
                              void* d_out, int out_size, void* d_ws, size_t ws_size,
                              hipStream_t stream)
{
    (void)in_sizes; (void)n_in; (void)out_size; (void)ws_size;
    const float* pot  = (const float*)d_in[0];
    const int*   vidx = (const int*)  d_in[1];
    const float* pv2f = (const float*)d_in[2];
    // d_in[3] = prv_f2v (unused by the reference)
    const float* pfb  = (const float*)d_in[4];
    const float* w1   = (const float*)d_in[5];
    const float* b1   = (const float*)d_in[6];
    const float* w2   = (const float*)d_in[7];
    const float* b2   = (const float*)d_in[8];

    // workspace layout (4-byte units; float2 arrays 8B-aligned by construction)
    float*  ws      = (float*)d_ws;
    float2* m       = (float2*)ws;              // 5*F float2   (1.5M floats)
    float2* vb      = m + 5 * F_N;              // V float2     (200k floats)
    int*   entries = (int*)(vb + V_N);          // F*K
    int*   offsets = entries + F_N * K_N;       // V
    int*   bsum    = offsets + V_N;             // <=512
    int*   cnt     = bsum + 512;                // V   } zeroed
    int*   fillc   = cnt + V_N;                 // V   } zeroed
    float* x       = (float*)(fillc + V_N);     // 330 } zeroed
    float* h       = x + MLP_N;                 // 330

    size_t zbytes = (size_t)(2 * V_N + MLP_N) * sizeof(float);
    hipMemsetAsync(cnt, 0, zbytes, stream);

    // CSR build
    k_hist<<<EBLK, 256, 0, stream>>>(vidx, cnt);
    k_bsum<<<VBLK, 256, 0, stream>>>(cnt, bsum);
    k_off <<<VBLK, 256, 0, stream>>>(cnt, bsum, offsets);
    k_fill<<<EBLK, 256, 0, stream>>>(vidx, offsets, fillc, entries);

    // m_1
    k_init<<<FBLK, 256, 0, stream>>>(pfb, pv2f, m);

    for (int it = 0; it < NITER; ++it) {
        k_gather<<<GBLK, 256, 0, stream>>>(m, cnt, offsets, entries, vb, x, it);
        if (it < NITER - 1)
            k_iter<false><<<FBLK, 256, 0, stream>>>(pot, vidx, m, vb, x, it);
        else
            k_iter<true><<<FBLK, 256, 0, stream>>>(pot, vidx, m, vb, x, it);
    }

    k_mlp1<<<MLP_N, 64, 0, stream>>>(x, w1, b1, h);
    k_mlp2<<<1, 64, 0, stream>>>(h, w2, b2, (float*)d_out);
}

// Round 4
// 292.783 us; speedup vs baseline: 6.2996x; 6.2996x over previous
//
#include <hip/hip_runtime.h>

#define F_N   150000
#define K_N   5
#define S_N   32
#define V_N   100000
#define NITER 5
#define MLP_N 330
#define SHIFTV (-500.0f)

#define FBLK  ((F_N + 255) / 256)       // 587
#define VBLK  ((V_N + 255) / 256)       // 391
#define GBLK  ((V_N * 2 + 255) / 256)   // 782  (2 threads per variable)
#define EBLK  ((F_N * K_N + 255) / 256) // 2930

__device__ __forceinline__ float lse2(float a, float b) {
    float mx = fmaxf(a, b);
    return mx + __logf(__expf(a - mx) + __expf(b - mx));
}

// ---------------- CSR build ------------------------------------------------
__global__ __launch_bounds__(256) void k_hist(
    const int* __restrict__ vidx, int* __restrict__ cnt)
{
    int i = blockIdx.x * 256 + threadIdx.x;
    if (i < F_N * K_N) atomicAdd(&cnt[vidx[i]], 1);
}

__global__ __launch_bounds__(256) void k_bsum(
    const int* __restrict__ cnt, int* __restrict__ bsum)
{
    __shared__ int s[256];
    int v = blockIdx.x * 256 + threadIdx.x;
    s[threadIdx.x] = (v < V_N) ? cnt[v] : 0;
    __syncthreads();
    #pragma unroll
    for (int off = 128; off >= 1; off >>= 1) {
        if (threadIdx.x < off) s[threadIdx.x] += s[threadIdx.x + off];
        __syncthreads();
    }
    if (threadIdx.x == 0) bsum[blockIdx.x] = s[0];
}

__global__ __launch_bounds__(256) void k_off(
    const int* __restrict__ cnt, const int* __restrict__ bsum,
    int* __restrict__ offsets)
{
    __shared__ int s[256];
    __shared__ int pre;
    int b = blockIdx.x, t = threadIdx.x;
    int acc = 0;
    for (int i = t; i < b; i += 256) acc += bsum[i];
    s[t] = acc; __syncthreads();
    #pragma unroll
    for (int off = 128; off >= 1; off >>= 1) {
        if (t < off) s[t] += s[t + off];
        __syncthreads();
    }
    if (t == 0) pre = s[0];
    __syncthreads();
    int base = pre;
    int v = b * 256 + t;
    int c = (v < V_N) ? cnt[v] : 0;
    s[t] = c; __syncthreads();
    #pragma unroll
    for (int off = 1; off < 256; off <<= 1) {
        int add = (t >= off) ? s[t - off] : 0;
        __syncthreads();
        s[t] += add;
        __syncthreads();
    }
    if (v < V_N) offsets[v] = base + s[t] - c;
}

__global__ __launch_bounds__(256) void k_fill(
    const int* __restrict__ vidx, const int* __restrict__ offsets,
    int* __restrict__ fillc, int* __restrict__ entries)
{
    int i = blockIdx.x * 256 + threadIdx.x;
    if (i >= F_N * K_N) return;
    int v = vidx[i];
    int f = i / K_N;
    int k = i - f * K_N;
    int pos = atomicAdd(&fillc[v], 1);
    entries[offsets[v] + pos] = k * F_N + f;   // pair-index into float2 m[5][F]
}

// ---------------- K0: m_1 from (prv_fb, prv_v2f) — no atomics ---------------
__global__ __launch_bounds__(256) void k_init(
    const float* __restrict__ prv_fb,   // [F][32]
    const float* __restrict__ prv_v2f,  // [F][5][2]
    float2*      __restrict__ m_out)    // [5][F] float2
{
    int f = blockIdx.x * 256 + threadIdx.x;
    if (f >= F_N) return;

    float fb[S_N];
    const float4* p4 = reinterpret_cast<const float4*>(prv_fb + (size_t)f * S_N);
    #pragma unroll
    for (int i = 0; i < S_N / 4; ++i) {
        float4 v = p4[i];
        fb[i*4+0] = v.x; fb[i*4+1] = v.y; fb[i*4+2] = v.z; fb[i*4+3] = v.w;
    }
    float M = fb[0];
    #pragma unroll
    for (int s = 1; s < S_N; ++s) M = fmaxf(M, fb[s]);
    float T = 0.0f;
    float S0[K_N] = {0.f, 0.f, 0.f, 0.f, 0.f};
    #pragma unroll
    for (int s = 0; s < S_N; ++s) {
        float t = __expf(fb[s] - M);
        T += t;
        #pragma unroll
        for (int k = 0; k < K_N; ++k)
            if (((s >> k) & 1) == 0) S0[k] += t;
    }
    #pragma unroll
    for (int k = 0; k < K_N; ++k) {
        float v0 = prv_v2f[(size_t)f * (K_N*2) + k*2 + 0];
        float v1 = prv_v2f[(size_t)f * (K_N*2) + k*2 + 1];
        float u0 = __logf(S0[k])     - v0;
        float u1 = __logf(T - S0[k]) - v1;
        float l  = lse2(u0, u1);
        m_out[k*F_N + f] = make_float2(u0 - l, u1 - l);
    }
}

// ---------------- per-iteration gather: vb_i = segsum(m_i); var_term partials
// 2 threads per variable; block-level LDS reduce; ONE partial store per block.
__global__ __launch_bounds__(256) void k_gather(
    const float2* __restrict__ m,        // [5][F]
    const int*    __restrict__ cnt,      // [V] (= deg)
    const int*    __restrict__ offsets,  // [V]
    const int*    __restrict__ entries,  // [F*K]
    float2*       __restrict__ vb,       // [V] raw (unnormalized)
    float2*       __restrict__ cpart,    // [NITER*GBLK] per-block var_term partials
    int iter)
{
    __shared__ float r0[256], r1[256];
    int t = blockIdx.x * 256 + threadIdx.x;
    int v = t >> 1, sub = t & 1;
    float a0 = 0.0f, a1 = 0.0f;
    int n = 0;
    if (v < V_N) {
        int off = offsets[v];
        n = cnt[v];
        for (int i = sub; i < n; i += 2) {
            float2 mm = m[entries[off + i]];
            a0 += mm.x; a1 += mm.y;
        }
    }
    a0 += __shfl_xor(a0, 1);
    a1 += __shfl_xor(a1, 1);
    float c0 = 0.0f, c1 = 0.0f;
    if (v < V_N && sub == 0) {
        vb[v] = make_float2(a0, a1);
        float l = lse2(a0, a1);
        float vb0 = a0 - l, vb1 = a1 - l;
        float dm1 = (float)n - 1.0f;
        c0 = dm1 * __expf(vb0) * vb0;
        c1 = dm1 * __expf(vb1) * vb1;
    }
    r0[threadIdx.x] = c0;
    r1[threadIdx.x] = c1;
    __syncthreads();
    #pragma unroll
    for (int off = 128; off >= 1; off >>= 1) {
        if (threadIdx.x < off) {
            r0[threadIdx.x] += r0[threadIdx.x + off];
            r1[threadIdx.x] += r1[threadIdx.x + off];
        }
        __syncthreads();
    }
    if (threadIdx.x == 0)
        cpart[iter * GBLK + blockIdx.x] = make_float2(r0[0], r1[0]);
}

// ---------------- reduce var_term partials into x ---------------------------
__global__ __launch_bounds__(256) void k_vt(
    const float2* __restrict__ cpart, float* __restrict__ x)
{
    __shared__ float r0[256], r1[256];
    int t = threadIdx.x;
    for (int it = 0; it < NITER; ++it) {
        float c0 = 0.0f, c1 = 0.0f;
        for (int b = t; b < GBLK; b += 256) {
            float2 p = cpart[it * GBLK + b];
            c0 += p.x; c1 += p.y;
        }
        r0[t] = c0; r1[t] = c1;
        __syncthreads();
        #pragma unroll
        for (int off = 128; off >= 1; off >>= 1) {
            if (t < off) { r0[t] += r0[t + off]; r1[t] += r1[t + off]; }
            __syncthreads();
        }
        if (t == 0) {
            x[it*66 + 64] = r0[0];
            x[it*66 + 65] = r1[0];
        }
        __syncthreads();
    }
}

// ---------------- fused factor iteration (no vb atomics) --------------------
template <bool LAST>
__global__ __launch_bounds__(256) void k_iter(
    const float*  __restrict__ pot,      // [F][32]
    const int*    __restrict__ vidx,     // [F][5]
    float2*       __restrict__ m,        // [5][F], updated in place
    const float2* __restrict__ vb,       // [V] raw
    float*        __restrict__ x,        // [330]
    int iter)
{
    const int lane = threadIdx.x & 63;
    __shared__ float red[256];

    int f = blockIdx.x * 256 + threadIdx.x;
    bool valid = f < F_N;
    int fc = valid ? f : (F_N - 1);

    float2 mm[K_N];
    #pragma unroll
    for (int k = 0; k < K_N; ++k) mm[k] = m[k*F_N + fc];
    int vi[K_N];
    #pragma unroll
    for (int k = 0; k < K_N; ++k) vi[k] = vidx[(size_t)fc * K_N + k];

    float v2f[K_N][2];
    #pragma unroll
    for (int k = 0; k < K_N; ++k) {
        float2 b = vb[vi[k]];
        float a0 = b.x - mm[k].x;
        float a1 = b.y - mm[k].y;
        float l = lse2(a0, a1);
        v2f[k][0] = a0 - l;
        v2f[k][1] = a1 - l;
    }

    float potr[S_N];
    const float4* p4 = reinterpret_cast<const float4*>(pot + (size_t)fc * S_N);
    #pragma unroll
    for (int i = 0; i < S_N / 4; ++i) {
        float4 v = p4[i];
        potr[i*4+0] = v.x; potr[i*4+1] = v.y; potr[i*4+2] = v.z; potr[i*4+3] = v.w;
    }

    float fb[S_N];
    #pragma unroll
    for (int s = 0; s < S_N; ++s) {
        float w = v2f[0][s & 1] + v2f[1][(s >> 1) & 1] + v2f[2][(s >> 2) & 1]
                + v2f[3][(s >> 3) & 1] + v2f[4][(s >> 4) & 1];
        fb[s] = potr[s] + w;
    }
    float M = fb[0];
    #pragma unroll
    for (int s = 1; s < S_N; ++s) M = fmaxf(M, fb[s]);

    float T = 0.0f;
    float S0[K_N] = {0.f, 0.f, 0.f, 0.f, 0.f};
    #pragma unroll
    for (int s = 0; s < S_N; ++s) {
        float t = __expf(fb[s] - M);
        T += t;
        #pragma unroll
        for (int k = 0; k < K_N; ++k)
            if (((s >> k) & 1) == 0) S0[k] += t;
    }

    if (!LAST) {
        #pragma unroll
        for (int k = 0; k < K_N; ++k) {
            float u0 = __logf(S0[k])     - v2f[k][0];
            float u1 = __logf(T - S0[k]) - v2f[k][1];
            float l  = lse2(u0, u1);
            if (valid) m[k*F_N + f] = make_float2(u0 - l, u1 - l);
        }
    }

    // ---- pooled features: energy[32] | fac_ent[32] ----
    float invT = 1.0f / T;
    float logT = __logf(T);
    float arr[2 * S_N];
    #pragma unroll
    for (int s = 0; s < S_N; ++s) {
        float p   = __expf(fb[s] - M) * invT;   // exp(fb_norm)
        float fbn = fb[s] - M - logT;           // normalized fb
        arr[s]       = valid ? p * potr[s] : 0.0f;
        arr[S_N + s] = valid ? -p * fbn    : 0.0f;
    }

    // recursive-halving reduce: 64 values over 64 lanes -> lane L holds sum of value L
    #pragma unroll
    for (int mk = 32; mk >= 1; mk >>= 1) {
        bool upper = (lane & mk) != 0;
        #pragma unroll
        for (int j = 0; j < mk; ++j) {
            float send = upper ? arr[j] : arr[j + mk];
            float recv = __shfl_xor(send, mk);
            float keep = upper ? arr[j + mk] : arr[j];
            arr[j] = keep + recv;
        }
    }

    red[threadIdx.x] = arr[0];
    __syncthreads();
    if (threadIdx.x < 64) {
        float s = red[threadIdx.x] + red[64 + threadIdx.x]
                + red[128 + threadIdx.x] + red[192 + threadIdx.x];
        atomicAdd(&x[iter*66 + threadIdx.x], s);   // 64 distinct addresses: fine
    }
}

// ---------------- MLP -------------------------------------------------------
__global__ __launch_bounds__(64) void k_mlp1(
    const float* __restrict__ x, const float* __restrict__ w1,
    const float* __restrict__ b1, float* __restrict__ h)
{
    int j = blockIdx.x;
    int lane = threadIdx.x;
    float s = 0.0f;
    for (int i = lane; i < MLP_N; i += 64) s += x[i] * w1[(size_t)j * MLP_N + i];
    #pragma unroll
    for (int mk = 32; mk >= 1; mk >>= 1) s += __shfl_xor(s, mk);
    if (lane == 0) h[j] = fmaxf(s + b1[j], SHIFTV);
}

__global__ __launch_bounds__(64) void k_mlp2(
    const float* __restrict__ h, const float* __restrict__ w2,
    const float* __restrict__ b2, float* __restrict__ out)
{
    int lane = threadIdx.x;
    float s = 0.0f;
    for (int i = lane; i < MLP_N; i += 64) s += h[i] * w2[i];
    #pragma unroll
    for (int mk = 32; mk >= 1; mk >>= 1) s += __shfl_xor(s, mk);
    if (lane == 0) out[0] = fmaxf(s + b2[0], SHIFTV);
}

// ---------------- launch -----------------------------------------------------
extern "C" void kernel_launch(void* const* d_in, const int* in_sizes, int n_in,
                              void* d_out, int out_size, void* d_ws, size_t ws_size,
                              hipStream_t stream)
{
    (void)in_sizes; (void)n_in; (void)out_size; (void)ws_size;
    const float* pot  = (const float*)d_in[0];
    const int*   vidx = (const int*)  d_in[1];
    const float* pv2f = (const float*)d_in[2];
    // d_in[3] = prv_f2v (unused by the reference)
    const float* pfb  = (const float*)d_in[4];
    const float* w1   = (const float*)d_in[5];
    const float* b1   = (const float*)d_in[6];
    const float* w2   = (const float*)d_in[7];
    const float* b2   = (const float*)d_in[8];

    // workspace layout (4-byte units; float2 arrays 8B-aligned by construction)
    float*  ws      = (float*)d_ws;
    float2* m       = (float2*)ws;              // 5*F float2
    float2* vb      = m + 5 * F_N;              // V float2
    float2* cpart   = vb + V_N;                 // NITER*GBLK float2
    int*   entries = (int*)(cpart + NITER*GBLK);// F*K
    int*   offsets = entries + F_N * K_N;       // V
    int*   bsum    = offsets + V_N;             // <=512
    int*   cnt     = bsum + 512;                // V   } zeroed
    int*   fillc   = cnt + V_N;                 // V   } zeroed
    float* x       = (float*)(fillc + V_N);     // 330 } zeroed
    float* h       = x + MLP_N;                 // 330

    size_t zbytes = (size_t)(2 * V_N + MLP_N) * sizeof(float);
    hipMemsetAsync(cnt, 0, zbytes, stream);

    // CSR build
    k_hist<<<EBLK, 256, 0, stream>>>(vidx, cnt);
    k_bsum<<<VBLK, 256, 0, stream>>>(cnt, bsum);
    k_off <<<VBLK, 256, 0, stream>>>(cnt, bsum, offsets);
    k_fill<<<EBLK, 256, 0, stream>>>(vidx, offsets, fillc, entries);

    // m_1
    k_init<<<FBLK, 256, 0, stream>>>(pfb, pv2f, m);

    for (int it = 0; it < NITER; ++it) {
        k_gather<<<GBLK, 256, 0, stream>>>(m, cnt, offsets, entries, vb, cpart, it);
        if (it < NITER - 1)
            k_iter<false><<<FBLK, 256, 0, stream>>>(pot, vidx, m, vb, x, it);
        else
            k_iter<true><<<FBLK, 256, 0, stream>>>(pot, vidx, m, vb, x, it);
    }

    k_vt<<<1, 256, 0, stream>>>(cpart, x);
    k_mlp1<<<MLP_N, 64, 0, stream>>>(x, w1, b1, h);
    k_mlp2<<<1, 64, 0, stream>>>(h, w2, b2, (float*)d_out);
}